// Round 4
// baseline (2219.754 us; speedup 1.0000x reference)
//
#include <hip/hip_runtime.h>
#include <hip/hip_bf16.h>
#include <stdint.h>

#define DEV __device__ __forceinline__

typedef uint32_t u32x4 __attribute__((ext_vector_type(4)));

// ---------------- Threefry-2x32, 4 independent chains interleaved ----------
// JAX partitionable path: counter=(0,n), draw = out0^out1 (verified bit-exact,
// absmax 8.0 rounds 1-3).
// Rotate: avoid v_alignbit_b32 (suspected quarter-rate VOP3). Use full-rate
//   t = x >> (32-r)                 (v_lshrrev_b32, inline const)
//   d = (x << r) + t                (v_lshl_add_u32; OR==ADD, disjoint bits)
// Inline asm pins the instruction so LLVM can't re-fuse into a rotate.

template <uint32_t R> DEV uint32_t rotl1(uint32_t x) {
  uint32_t t = x >> (32u - R);
  uint32_t d;
  asm("v_lshl_add_u32 %0, %1, %2, %3" : "=v"(d) : "v"(x), "i"(R), "v"(t));
  return d;
}

template <uint32_t R> DEV u32x4 rotl4(u32x4 x) {
  u32x4 o;
  o.x = rotl1<R>(x.x); o.y = rotl1<R>(x.y);
  o.z = rotl1<R>(x.z); o.w = rotl1<R>(x.w);
  return o;
}

DEV u32x4 tf_bits4(uint32_t k0, uint32_t k1, u32x4 n) {
  uint32_t ks2 = k0 ^ k1 ^ 0x1BD11BDAu;
  u32x4 x1 = n + k1;
  u32x4 x0 = x1 + k0;                    // round-1 add folded
  x1 = rotl4<13>(x1) ^ x0;
#define TF_R4(r) { x0 += x1; x1 = rotl4<r>(x1) ^ x0; }
  TF_R4(15) TF_R4(26) TF_R4(6)            x0 += k1;  x1 += ks2 + 1u;
  TF_R4(17) TF_R4(29) TF_R4(16) TF_R4(24) x0 += ks2; x1 += k0 + 2u;
  TF_R4(13) TF_R4(15) TF_R4(26) TF_R4(6)  x0 += k0;  x1 += k1 + 3u;
  TF_R4(17) TF_R4(29) TF_R4(16) TF_R4(24) x0 += k1;  x1 += ks2 + 4u;
  TF_R4(13) TF_R4(15) TF_R4(26) TF_R4(6)  x0 += ks2; x1 += k0 + 5u;
#undef TF_R4
  return x0 ^ x1;
}

// constexpr host-side threefry for fold_in key derivation (compile-time)
struct KP { uint32_t a, b; };
constexpr KP tf_pair_ct(uint32_t k0, uint32_t k1, uint32_t c0, uint32_t c1) {
  uint32_t ks2 = k0 ^ k1 ^ 0x1BD11BDAu;
  uint32_t x0 = c0 + k0, x1 = c1 + k1;
  const uint32_t R[2][4] = {{13u,15u,26u,6u},{17u,29u,16u,24u}};
  uint32_t ks[3] = {k0, k1, ks2};
  for (int g = 0; g < 5; ++g) {
    for (int j = 0; j < 4; ++j) {
      x0 += x1;
      uint32_t r = R[g & 1][j];
      x1 = ((x1 << r) | (x1 >> (32u - r))) ^ x0;
    }
    x0 += ks[(g + 1) % 3];
    x1 += ks[(g + 2) % 3] + (uint32_t)(g + 1);
  }
  return {x0, x1};
}

template <int H> struct KeyArr { uint32_t k0[H]; uint32_t k1[H]; };
template <int H> constexpr KeyArr<H> make_keys(uint32_t seed) {
  KeyArr<H> K{};
  for (int i = 0; i < H; ++i) {
    KP p = tf_pair_ct(0u, seed, 0u, (uint32_t)i);
    K.k0[i] = p.a; K.k1[i] = p.b;
  }
  return K;
}

constexpr KeyArr<10> XE = make_keys<10>(0u);
constexpr KeyArr<6>  XF = make_keys<6>(1u);
constexpr KeyArr<12> WE = make_keys<12>(2u);
constexpr KeyArr<8>  WF = make_keys<8>(3u);

#define EXP_MASK  0x7F800000u
#define FRAC_MASK 0x007FFFFFu

// flip 4 consecutive elements (flat index n0..n0+3); returns flipped fp32 bits
template <int HE, int HF>
DEV u32x4 flip_bits4(u32x4 vbits, const KeyArr<HE>& KE, const KeyArr<HF>& KF,
                     uint32_t n0, float zero_t) {
  u32x4 n = {n0, n0 + 1u, n0 + 2u, n0 + 3u};
  u32x4 me = {EXP_MASK, EXP_MASK, EXP_MASK, EXP_MASK};
#pragma unroll
  for (int h = 0; h < HE; ++h) me &= tf_bits4(KE.k0[h], KE.k1[h], n);
  u32x4 mf = {FRAC_MASK, FRAC_MASK, FRAC_MASK, FRAC_MASK};
#pragma unroll
  for (int h = 0; h < HF; ++h) mf &= tf_bits4(KF.k0[h], KF.k1[h], n);
  u32x4 bits = vbits ^ (me | mf);
  u32x4 out;
#pragma unroll
  for (int e = 0; e < 4; ++e) {
    uint32_t b = bits[e];
    // NaN/inf fail (|y| <= t) anyway -> finite check is redundant
    float ay = __uint_as_float(b & 0x7FFFFFFFu);
    out[e] = (ay <= zero_t) ? b : 0u;
  }
  return out;
}

// round fp32 raw bits to bf16-RNE, pack pair into one u32 (lo=first)
DEV uint32_t pack2_bf16(uint32_t u0, uint32_t u1) {
  u0 += 0x7FFFu + ((u0 >> 16) & 1u);
  u1 += 0x7FFFu + ((u1 >> 16) & 1u);
  return __builtin_amdgcn_perm(u1, u0, 0x07060302u);
}

typedef float f32x4_v __attribute__((ext_vector_type(4)));

// ---------------- Stage 1: bitflip(x) -> bf16 (4 elems/thread/iter) ---------
__global__ __launch_bounds__(256)
void k_bitflip_x(const u32x4* __restrict__ x, uint2* __restrict__ xb, int n_quads) {
  int stride = gridDim.x * blockDim.x;
#pragma unroll 1
  for (int q = blockIdx.x * blockDim.x + threadIdx.x; q < n_quads; q += stride) {
    u32x4 v = x[q];
    u32x4 b = flip_bits4<10, 6>(v, XE, XF, (uint32_t)q * 4u, 1000.0f);
    uint2 o;
    o.x = pack2_bf16(b.x, b.y);
    o.y = pack2_bf16(b.z, b.w);
    xb[q] = o;
  }
}

// ---------------- Stage 2: w = weight + loraB@loraA, bitflip -> bf16 --------
__global__ __launch_bounds__(256)
void k_make_wb(const f32x4_v* __restrict__ weight, const float* __restrict__ lA,
               const float* __restrict__ lB, uint2* __restrict__ wb, int n_quads) {
  int stride = gridDim.x * blockDim.x;
#pragma unroll 1
  for (int q = blockIdx.x * blockDim.x + threadIdx.x; q < n_quads; q += stride) {
    uint32_t n0 = (uint32_t)q * 4u;
    int o = (int)(n0 >> 12);          // D_IN = 4096
    int c = (int)(n0 & 4095u);
    f32x4_v acc = weight[q];
#pragma unroll
    for (int r = 0; r < 32; ++r) {
      f32x4_v a = *(const f32x4_v*)&lA[(r << 12) + c];
      float  b = lB[(o << 5) + r];
      acc.x += b * a.x; acc.y += b * a.y;
      acc.z += b * a.z; acc.w += b * a.w;
    }
    u32x4 vb = {__float_as_uint(acc.x), __float_as_uint(acc.y),
                __float_as_uint(acc.z), __float_as_uint(acc.w)};
    u32x4 bo = flip_bits4<12, 8>(vb, WE, WF, n0, 100.0f);
    uint2 ov;
    ov.x = pack2_bf16(bo.x, bo.y);
    ov.y = pack2_bf16(bo.z, bo.w);
    wb[q] = ov;
  }
}

// ---------------- Stage 3: GEMM  C[m,n] = sum_k A[m,k]*B[n,k]  (m97 structure)
typedef __bf16 bf16x8_t __attribute__((ext_vector_type(8)));
typedef float  f32x4_t  __attribute__((ext_vector_type(4)));

DEV void gload_lds16(const uint16_t* g, uint16_t* l) {
  __builtin_amdgcn_global_load_lds((const __attribute__((address_space(1))) void*)g,
                                   (__attribute__((address_space(3))) void*)l, 16, 0, 0);
}

__global__ __launch_bounds__(256)
void k_gemm(const uint16_t* __restrict__ A, const uint16_t* __restrict__ B,
            float* __restrict__ C, int M, int N, int K) {
  __shared__ __align__(16) uint16_t As[128 * 32];
  __shared__ __align__(16) uint16_t Bs[128 * 32];

  int bid = blockIdx.x;
  int cpx = gridDim.x >> 3;
  int wg  = (bid & 7) * cpx + (bid >> 3);
  int ntiles = N >> 7;
  int tm = (wg / ntiles) << 7;
  int tn = (wg % ntiles) << 7;

  int tid  = threadIdx.x;
  int lane = tid & 63;
  int wid  = tid >> 6;
  int wm = (wid >> 1) << 6;
  int wn = (wid & 1) << 6;

  f32x4_t acc[4][4] = {};

  int fr = lane & 15;
  int kg = (lane >> 4) << 3;

  int srow = lane >> 2;
  int scol = (lane & 3) << 3;
  const uint16_t* gA = A + (size_t)(tm + (wid << 5) + srow) * K + scol;
  const uint16_t* gB = B + (size_t)(tn + (wid << 5) + srow) * K + scol;
  uint16_t* lA0 = &As[((wid << 5) + 0) * 32];
  uint16_t* lA1 = &As[((wid << 5) + 16) * 32];
  uint16_t* lB0 = &Bs[((wid << 5) + 0) * 32];
  uint16_t* lB1 = &Bs[((wid << 5) + 16) * 32];

  for (int k0 = 0; k0 < K; k0 += 32) {
    gload_lds16(gA, lA0);
    gload_lds16(gA + 16 * (size_t)K, lA1);
    gload_lds16(gB, lB0);
    gload_lds16(gB + 16 * (size_t)K, lB1);
    __syncthreads();

    bf16x8_t af[4], bfr[4];
#pragma unroll
    for (int m = 0; m < 4; ++m)
      af[m] = *(const bf16x8_t*)&As[(wm + (m << 4) + fr) * 32 + kg];
#pragma unroll
    for (int n = 0; n < 4; ++n)
      bfr[n] = *(const bf16x8_t*)&Bs[(wn + (n << 4) + fr) * 32 + kg];

#pragma unroll
    for (int m = 0; m < 4; ++m)
#pragma unroll
      for (int n = 0; n < 4; ++n)
        acc[m][n] = __builtin_amdgcn_mfma_f32_16x16x32_bf16(af[m], bfr[n], acc[m][n], 0, 0, 0);

    __syncthreads();
    gA += 32; gB += 32;
  }

  int crow = tm + wm + ((lane >> 4) << 2);
  int ccol = tn + wn + (lane & 15);
#pragma unroll
  for (int m = 0; m < 4; ++m)
#pragma unroll
    for (int n = 0; n < 4; ++n)
#pragma unroll
      for (int j = 0; j < 4; ++j)
        C[(size_t)(crow + (m << 4) + j) * N + (ccol + (n << 4))] = acc[m][n][j];
}

// ---------------- launch ----------------
extern "C" void kernel_launch(void* const* d_in, const int* in_sizes, int n_in,
                              void* d_out, int out_size, void* d_ws, size_t ws_size,
                              hipStream_t stream) {
  const float* x      = (const float*)d_in[0];
  const float* weight = (const float*)d_in[1];
  const float* lA     = (const float*)d_in[2];
  const float* lB     = (const float*)d_in[3];
  float* out = (float*)d_out;

  const int M = 4 * 2048;   // B*S
  const int N = 4096;       // D_OUT
  const int K = 4096;       // D_IN

  size_t need = (size_t)M * K * 2 + (size_t)N * K * 2;
  if (ws_size < need) return;

  uint16_t* xb = (uint16_t*)d_ws;
  uint16_t* wb = xb + (size_t)M * K;

  k_bitflip_x<<<2048, 256, 0, stream>>>((const u32x4*)x, (uint2*)xb, (M * K) / 4);
  k_make_wb<<<2048, 256, 0, stream>>>((const f32x4_v*)weight, lA, lB, (uint2*)wb, (N * K) / 4);

  dim3 grid((M / 128) * (N / 128));   // 2048, divisible by 8
  k_gemm<<<grid, 256, 0, stream>>>(xb, wb, out, M, N, K);
}

// Round 5
// 1783.725 us; speedup vs baseline: 1.2444x; 1.2444x over previous
//
#include <hip/hip_runtime.h>
#include <hip/hip_bf16.h>
#include <stdint.h>

#define DEV __device__ __forceinline__

typedef uint32_t u32x4 __attribute__((ext_vector_type(4)));

// ---------------- Threefry-2x32, 4 chains, folded injections --------------
// JAX partitionable path: counter=(0,n), draw = out0^out1 (bit-exact, absmax
// 8.0 rounds 1-4). alignbit rotate confirmed full-rate (round-4 A/B).
// Group-boundary fold: {x0+=kA; x1+=kB; x0+=x1} -> {x1+=kB; x0=x0+x1+kA}
// (v_add3_u32). 67 ops/draw vs 72.

DEV uint32_t rotl1(uint32_t x, uint32_t r) {
  return __builtin_amdgcn_alignbit(x, x, 32u - r);
}
DEV u32x4 rotl4(u32x4 x, uint32_t r) {
  u32x4 o;
  o.x = rotl1(x.x, r); o.y = rotl1(x.y, r);
  o.z = rotl1(x.z, r); o.w = rotl1(x.w, r);
  return o;
}

DEV u32x4 tf_bits4(uint32_t k0, uint32_t k1, u32x4 n) {
  const uint32_t ks2 = k0 ^ k1 ^ 0x1BD11BDAu;
  u32x4 x1 = n + k1;
  u32x4 x0 = x1 + k0;                    // round-1 "x0 += x1" folded
  x1 = rotl4(x1, 13) ^ x0;
#define TF_R4(r) { x0 += x1; x1 = rotl4(x1, r) ^ x0; }
  // rounds 2-4
  TF_R4(15) TF_R4(26) TF_R4(6)
  // boundary 1: x0+=k1; x1+=ks2+1; round5(17)
  x1 += ks2 + 1u;  x0 = x0 + x1 + k1;  x1 = rotl4(x1, 17) ^ x0;
  TF_R4(29) TF_R4(16) TF_R4(24)
  // boundary 2: x0+=ks2; x1+=k0+2; round9(13)
  x1 += k0 + 2u;   x0 = x0 + x1 + ks2; x1 = rotl4(x1, 13) ^ x0;
  TF_R4(15) TF_R4(26) TF_R4(6)
  // boundary 3: x0+=k0; x1+=k1+3; round13(17)
  x1 += k1 + 3u;   x0 = x0 + x1 + k0;  x1 = rotl4(x1, 17) ^ x0;
  TF_R4(29) TF_R4(16) TF_R4(24)
  // boundary 4: x0+=k1; x1+=ks2+4; round17(13)
  x1 += ks2 + 4u;  x0 = x0 + x1 + k1;  x1 = rotl4(x1, 13) ^ x0;
  TF_R4(15) TF_R4(26) TF_R4(6)
#undef TF_R4
  x0 += ks2; x1 += k0 + 5u;
  return x0 ^ x1;
}

// constexpr host-side threefry for fold_in key derivation (compile-time)
struct KP { uint32_t a, b; };
constexpr KP tf_pair_ct(uint32_t k0, uint32_t k1, uint32_t c0, uint32_t c1) {
  uint32_t ks2 = k0 ^ k1 ^ 0x1BD11BDAu;
  uint32_t x0 = c0 + k0, x1 = c1 + k1;
  const uint32_t R[2][4] = {{13u,15u,26u,6u},{17u,29u,16u,24u}};
  uint32_t ks[3] = {k0, k1, ks2};
  for (int g = 0; g < 5; ++g) {
    for (int j = 0; j < 4; ++j) {
      x0 += x1;
      uint32_t r = R[g & 1][j];
      x1 = ((x1 << r) | (x1 >> (32u - r))) ^ x0;
    }
    x0 += ks[(g + 1) % 3];
    x1 += ks[(g + 2) % 3] + (uint32_t)(g + 1);
  }
  return {x0, x1};
}

template <int H> struct KeyArr { uint32_t k0[H]; uint32_t k1[H]; };
template <int H> constexpr KeyArr<H> make_keys(uint32_t seed) {
  KeyArr<H> K{};
  for (int i = 0; i < H; ++i) {
    KP p = tf_pair_ct(0u, seed, 0u, (uint32_t)i);
    K.k0[i] = p.a; K.k1[i] = p.b;
  }
  return K;
}

constexpr KeyArr<10> XE = make_keys<10>(0u);
constexpr KeyArr<6>  XF = make_keys<6>(1u);
constexpr KeyArr<12> WE = make_keys<12>(2u);
constexpr KeyArr<8>  WF = make_keys<8>(3u);

#define EXP_MASK  0x7F800000u
#define FRAC_MASK 0x007FFFFFu

// flip 4 consecutive elements (flat index n0..n0+3); returns flipped fp32 bits
template <int HE, int HF>
DEV u32x4 flip_bits4(u32x4 vbits, const KeyArr<HE>& KE, const KeyArr<HF>& KF,
                     uint32_t n0, float zero_t) {
  u32x4 n = {n0, n0 + 1u, n0 + 2u, n0 + 3u};
  u32x4 me = {EXP_MASK, EXP_MASK, EXP_MASK, EXP_MASK};
#pragma unroll
  for (int h = 0; h < HE; ++h) me &= tf_bits4(KE.k0[h], KE.k1[h], n);
  u32x4 mf = {FRAC_MASK, FRAC_MASK, FRAC_MASK, FRAC_MASK};
#pragma unroll
  for (int h = 0; h < HF; ++h) mf &= tf_bits4(KF.k0[h], KF.k1[h], n);
  u32x4 bits = vbits ^ (me | mf);
  u32x4 out;
#pragma unroll
  for (int e = 0; e < 4; ++e) {
    uint32_t b = bits[e];
    // NaN/inf fail (|y| <= t) anyway -> finite check is redundant
    float ay = __uint_as_float(b & 0x7FFFFFFFu);
    out[e] = (ay <= zero_t) ? b : 0u;
  }
  return out;
}

// round fp32 raw bits to bf16-RNE, pack pair into one u32 (lo=first)
DEV uint32_t pack2_bf16(uint32_t u0, uint32_t u1) {
  u0 += 0x7FFFu + ((u0 >> 16) & 1u);
  u1 += 0x7FFFu + ((u1 >> 16) & 1u);
  return __builtin_amdgcn_perm(u1, u0, 0x07060302u);
}

typedef float f32x4_v __attribute__((ext_vector_type(4)));

// ---------------- Stage 1: bitflip(x) -> bf16 (4 elems/thread/iter) ---------
__global__ __launch_bounds__(256)
void k_bitflip_x(const u32x4* __restrict__ x, uint2* __restrict__ xb, int n_quads) {
  int stride = gridDim.x * blockDim.x;
#pragma unroll 1
  for (int q = blockIdx.x * blockDim.x + threadIdx.x; q < n_quads; q += stride) {
    u32x4 v = x[q];
    u32x4 b = flip_bits4<10, 6>(v, XE, XF, (uint32_t)q * 4u, 1000.0f);
    uint2 o;
    o.x = pack2_bf16(b.x, b.y);
    o.y = pack2_bf16(b.z, b.w);
    xb[q] = o;
  }
}

// ---------------- Stage 2: w = weight + loraB@loraA, bitflip -> bf16 --------
__global__ __launch_bounds__(256)
void k_make_wb(const f32x4_v* __restrict__ weight, const float* __restrict__ lA,
               const float* __restrict__ lB, uint2* __restrict__ wb, int n_quads) {
  int stride = gridDim.x * blockDim.x;
#pragma unroll 1
  for (int q = blockIdx.x * blockDim.x + threadIdx.x; q < n_quads; q += stride) {
    uint32_t n0 = (uint32_t)q * 4u;
    int o = (int)(n0 >> 12);          // D_IN = 4096
    int c = (int)(n0 & 4095u);
    f32x4_v acc = weight[q];
#pragma unroll
    for (int r = 0; r < 32; ++r) {
      f32x4_v a = *(const f32x4_v*)&lA[(r << 12) + c];
      float  b = lB[(o << 5) + r];
      acc.x += b * a.x; acc.y += b * a.y;
      acc.z += b * a.z; acc.w += b * a.w;
    }
    u32x4 vb = {__float_as_uint(acc.x), __float_as_uint(acc.y),
                __float_as_uint(acc.z), __float_as_uint(acc.w)};
    u32x4 bo = flip_bits4<12, 8>(vb, WE, WF, n0, 100.0f);
    uint2 ov;
    ov.x = pack2_bf16(bo.x, bo.y);
    ov.y = pack2_bf16(bo.z, bo.w);
    wb[q] = ov;
  }
}

// ---------------- Stage 3: GEMM  C[m,n] = sum_k A[m,k]*B[n,k]  (m97 structure)
typedef __bf16 bf16x8_t __attribute__((ext_vector_type(8)));
typedef float  f32x4_t  __attribute__((ext_vector_type(4)));

DEV void gload_lds16(const uint16_t* g, uint16_t* l) {
  __builtin_amdgcn_global_load_lds((const __attribute__((address_space(1))) void*)g,
                                   (__attribute__((address_space(3))) void*)l, 16, 0, 0);
}

__global__ __launch_bounds__(256)
void k_gemm(const uint16_t* __restrict__ A, const uint16_t* __restrict__ B,
            float* __restrict__ C, int M, int N, int K) {
  __shared__ __align__(16) uint16_t As[128 * 32];
  __shared__ __align__(16) uint16_t Bs[128 * 32];

  int bid = blockIdx.x;
  int cpx = gridDim.x >> 3;
  int wg  = (bid & 7) * cpx + (bid >> 3);
  int ntiles = N >> 7;
  int tm = (wg / ntiles) << 7;
  int tn = (wg % ntiles) << 7;

  int tid  = threadIdx.x;
  int lane = tid & 63;
  int wid  = tid >> 6;
  int wm = (wid >> 1) << 6;
  int wn = (wid & 1) << 6;

  f32x4_t acc[4][4] = {};

  int fr = lane & 15;
  int kg = (lane >> 4) << 3;

  int srow = lane >> 2;
  int scol = (lane & 3) << 3;
  const uint16_t* gA = A + (size_t)(tm + (wid << 5) + srow) * K + scol;
  const uint16_t* gB = B + (size_t)(tn + (wid << 5) + srow) * K + scol;
  uint16_t* lA0 = &As[((wid << 5) + 0) * 32];
  uint16_t* lA1 = &As[((wid << 5) + 16) * 32];
  uint16_t* lB0 = &Bs[((wid << 5) + 0) * 32];
  uint16_t* lB1 = &Bs[((wid << 5) + 16) * 32];

  for (int k0 = 0; k0 < K; k0 += 32) {
    gload_lds16(gA, lA0);
    gload_lds16(gA + 16 * (size_t)K, lA1);
    gload_lds16(gB, lB0);
    gload_lds16(gB + 16 * (size_t)K, lB1);
    __syncthreads();

    bf16x8_t af[4], bfr[4];
#pragma unroll
    for (int m = 0; m < 4; ++m)
      af[m] = *(const bf16x8_t*)&As[(wm + (m << 4) + fr) * 32 + kg];
#pragma unroll
    for (int n = 0; n < 4; ++n)
      bfr[n] = *(const bf16x8_t*)&Bs[(wn + (n << 4) + fr) * 32 + kg];

#pragma unroll
    for (int m = 0; m < 4; ++m)
#pragma unroll
      for (int n = 0; n < 4; ++n)
        acc[m][n] = __builtin_amdgcn_mfma_f32_16x16x32_bf16(af[m], bfr[n], acc[m][n], 0, 0, 0);

    __syncthreads();
    gA += 32; gB += 32;
  }

  int crow = tm + wm + ((lane >> 4) << 2);
  int ccol = tn + wn + (lane & 15);
#pragma unroll
  for (int m = 0; m < 4; ++m)
#pragma unroll
    for (int n = 0; n < 4; ++n)
#pragma unroll
      for (int j = 0; j < 4; ++j)
        C[(size_t)(crow + (m << 4) + j) * N + (ccol + (n << 4))] = acc[m][n][j];
}

// ---------------- launch ----------------
extern "C" void kernel_launch(void* const* d_in, const int* in_sizes, int n_in,
                              void* d_out, int out_size, void* d_ws, size_t ws_size,
                              hipStream_t stream) {
  const float* x      = (const float*)d_in[0];
  const float* weight = (const float*)d_in[1];
  const float* lA     = (const float*)d_in[2];
  const float* lB     = (const float*)d_in[3];
  float* out = (float*)d_out;

  const int M = 4 * 2048;   // B*S
  const int N = 4096;       // D_OUT
  const int K = 4096;       // D_IN

  size_t need = (size_t)M * K * 2 + (size_t)N * K * 2;
  if (ws_size < need) return;

  uint16_t* xb = (uint16_t*)d_ws;
  uint16_t* wb = xb + (size_t)M * K;

  k_bitflip_x<<<2048, 256, 0, stream>>>((const u32x4*)x, (uint2*)xb, (M * K) / 4);
  k_make_wb<<<2048, 256, 0, stream>>>((const f32x4_v*)weight, lA, lB, (uint2*)wb, (N * K) / 4);

  dim3 grid((M / 128) * (N / 128));   // 2048, divisible by 8
  k_gemm<<<grid, 256, 0, stream>>>(xb, wb, out, M, N, K);
}

// Round 6
// 1657.779 us; speedup vs baseline: 1.3390x; 1.0760x over previous
//
#include <hip/hip_runtime.h>
#include <hip/hip_bf16.h>
#include <stdint.h>

#define DEV __device__ __forceinline__

typedef uint32_t u32x4 __attribute__((ext_vector_type(4)));

// ---------------- Threefry-2x32, 4 chains, folded injections --------------
// JAX partitionable path: counter=(0,n), draw = out0^out1 (bit-exact, absmax
// 8.0 rounds 1-5). alignbit rotate confirmed full-rate (round-4 A/B).
// Issue-bound at ~80% of practical VALU ceiling (round-5 analysis) - closed.

DEV uint32_t rotl1(uint32_t x, uint32_t r) {
  return __builtin_amdgcn_alignbit(x, x, 32u - r);
}
DEV u32x4 rotl4(u32x4 x, uint32_t r) {
  u32x4 o;
  o.x = rotl1(x.x, r); o.y = rotl1(x.y, r);
  o.z = rotl1(x.z, r); o.w = rotl1(x.w, r);
  return o;
}

DEV u32x4 tf_bits4(uint32_t k0, uint32_t k1, u32x4 n) {
  const uint32_t ks2 = k0 ^ k1 ^ 0x1BD11BDAu;
  u32x4 x1 = n + k1;
  u32x4 x0 = x1 + k0;
  x1 = rotl4(x1, 13) ^ x0;
#define TF_R4(r) { x0 += x1; x1 = rotl4(x1, r) ^ x0; }
  TF_R4(15) TF_R4(26) TF_R4(6)
  x1 += ks2 + 1u;  x0 = x0 + x1 + k1;  x1 = rotl4(x1, 17) ^ x0;
  TF_R4(29) TF_R4(16) TF_R4(24)
  x1 += k0 + 2u;   x0 = x0 + x1 + ks2; x1 = rotl4(x1, 13) ^ x0;
  TF_R4(15) TF_R4(26) TF_R4(6)
  x1 += k1 + 3u;   x0 = x0 + x1 + k0;  x1 = rotl4(x1, 17) ^ x0;
  TF_R4(29) TF_R4(16) TF_R4(24)
  x1 += ks2 + 4u;  x0 = x0 + x1 + k1;  x1 = rotl4(x1, 13) ^ x0;
  TF_R4(15) TF_R4(26) TF_R4(6)
#undef TF_R4
  x0 += ks2; x1 += k0 + 5u;
  return x0 ^ x1;
}

struct KP { uint32_t a, b; };
constexpr KP tf_pair_ct(uint32_t k0, uint32_t k1, uint32_t c0, uint32_t c1) {
  uint32_t ks2 = k0 ^ k1 ^ 0x1BD11BDAu;
  uint32_t x0 = c0 + k0, x1 = c1 + k1;
  const uint32_t R[2][4] = {{13u,15u,26u,6u},{17u,29u,16u,24u}};
  uint32_t ks[3] = {k0, k1, ks2};
  for (int g = 0; g < 5; ++g) {
    for (int j = 0; j < 4; ++j) {
      x0 += x1;
      uint32_t r = R[g & 1][j];
      x1 = ((x1 << r) | (x1 >> (32u - r))) ^ x0;
    }
    x0 += ks[(g + 1) % 3];
    x1 += ks[(g + 2) % 3] + (uint32_t)(g + 1);
  }
  return {x0, x1};
}

template <int H> struct KeyArr { uint32_t k0[H]; uint32_t k1[H]; };
template <int H> constexpr KeyArr<H> make_keys(uint32_t seed) {
  KeyArr<H> K{};
  for (int i = 0; i < H; ++i) {
    KP p = tf_pair_ct(0u, seed, 0u, (uint32_t)i);
    K.k0[i] = p.a; K.k1[i] = p.b;
  }
  return K;
}

constexpr KeyArr<10> XE = make_keys<10>(0u);
constexpr KeyArr<6>  XF = make_keys<6>(1u);
constexpr KeyArr<12> WE = make_keys<12>(2u);
constexpr KeyArr<8>  WF = make_keys<8>(3u);

#define EXP_MASK  0x7F800000u
#define FRAC_MASK 0x007FFFFFu

template <int HE, int HF>
DEV u32x4 flip_bits4(u32x4 vbits, const KeyArr<HE>& KE, const KeyArr<HF>& KF,
                     uint32_t n0, float zero_t) {
  u32x4 n = {n0, n0 + 1u, n0 + 2u, n0 + 3u};
  u32x4 me = {EXP_MASK, EXP_MASK, EXP_MASK, EXP_MASK};
#pragma unroll
  for (int h = 0; h < HE; ++h) me &= tf_bits4(KE.k0[h], KE.k1[h], n);
  u32x4 mf = {FRAC_MASK, FRAC_MASK, FRAC_MASK, FRAC_MASK};
#pragma unroll
  for (int h = 0; h < HF; ++h) mf &= tf_bits4(KF.k0[h], KF.k1[h], n);
  u32x4 bits = vbits ^ (me | mf);
  u32x4 out;
#pragma unroll
  for (int e = 0; e < 4; ++e) {
    uint32_t b = bits[e];
    float ay = __uint_as_float(b & 0x7FFFFFFFu);
    out[e] = (ay <= zero_t) ? b : 0u;   // NaN/inf fail compare -> 0
  }
  return out;
}

DEV uint32_t pack2_bf16(uint32_t u0, uint32_t u1) {
  u0 += 0x7FFFu + ((u0 >> 16) & 1u);
  u1 += 0x7FFFu + ((u1 >> 16) & 1u);
  return __builtin_amdgcn_perm(u1, u0, 0x07060302u);
}

typedef float f32x4_v __attribute__((ext_vector_type(4)));

// ---------------- Stage 1: bitflip(x) -> bf16 ----------------
__global__ __launch_bounds__(256)
void k_bitflip_x(const u32x4* __restrict__ x, uint2* __restrict__ xb, int n_quads) {
  int stride = gridDim.x * blockDim.x;
#pragma unroll 1
  for (int q = blockIdx.x * blockDim.x + threadIdx.x; q < n_quads; q += stride) {
    u32x4 v = x[q];
    u32x4 b = flip_bits4<10, 6>(v, XE, XF, (uint32_t)q * 4u, 1000.0f);
    uint2 o;
    o.x = pack2_bf16(b.x, b.y);
    o.y = pack2_bf16(b.z, b.w);
    xb[q] = o;
  }
}

// ---------------- Stage 2: w = weight + loraB@loraA, bitflip -> bf16 --------
__global__ __launch_bounds__(256)
void k_make_wb(const f32x4_v* __restrict__ weight, const float* __restrict__ lA,
               const float* __restrict__ lB, uint2* __restrict__ wb, int n_quads) {
  int stride = gridDim.x * blockDim.x;
#pragma unroll 1
  for (int q = blockIdx.x * blockDim.x + threadIdx.x; q < n_quads; q += stride) {
    uint32_t n0 = (uint32_t)q * 4u;
    int o = (int)(n0 >> 12);          // D_IN = 4096
    int c = (int)(n0 & 4095u);
    f32x4_v acc = weight[q];
#pragma unroll
    for (int r = 0; r < 32; ++r) {
      f32x4_v a = *(const f32x4_v*)&lA[(r << 12) + c];
      float  b = lB[(o << 5) + r];
      acc.x += b * a.x; acc.y += b * a.y;
      acc.z += b * a.z; acc.w += b * a.w;
    }
    u32x4 vb = {__float_as_uint(acc.x), __float_as_uint(acc.y),
                __float_as_uint(acc.z), __float_as_uint(acc.w)};
    u32x4 bo = flip_bits4<12, 8>(vb, WE, WF, n0, 100.0f);
    uint2 ov;
    ov.x = pack2_bf16(bo.x, bo.y);
    ov.y = pack2_bf16(bo.z, bo.w);
    wb[q] = ov;
  }
}

// ---------------- Stage 3: 256x256 8-wave GEMM, counted-vmcnt pipeline ------
// C[m,n] = sum_k A[m,k]*B[n,k].  BM=BN=256, BK=64, 8 waves (2Mx4N), LDS 128KB
// double-buffered. XOR slot-swizzle (byte ^= (row&7)<<4) applied as:
// linear LDS dest + inverse-swizzled GLOBAL source (stage) + swizzled ds_read.
typedef __bf16 bf16x8_t __attribute__((ext_vector_type(8)));
typedef float  f32x4_t  __attribute__((ext_vector_type(4)));

DEV void gload_lds16(const uint16_t* g, uint16_t* l) {
  __builtin_amdgcn_global_load_lds((const __attribute__((address_space(1))) void*)g,
                                   (__attribute__((address_space(3))) void*)l, 16, 0, 0);
}

// stage one 256x64 bf16 tile (32KB): 4 global_load_lds per thread.
DEV void stage_tile(const uint16_t* __restrict__ G, int grow0, int k0, int K,
                    uint16_t* lds_tile, int lane, int wid) {
#pragma unroll
  for (int c = 0; c < 4; ++c) {
    int obase = c * 8192 + wid * 1024;          // wave-uniform LDS byte base
    int row   = (obase >> 7) + (lane >> 3);     // 128B per row
    int slot  = lane & 7;                       // 16B slot within row
    const uint16_t* src = G + (size_t)(grow0 + row) * K + k0
                            + ((slot ^ (row & 7)) << 3);   // inverse swizzle
    gload_lds16(src, (uint16_t*)((char*)lds_tile + obase)); // HW adds lane*16
  }
}

DEV bf16x8_t read_frag(const uint16_t* tile, int row, int kk, int lane) {
  int slot = (kk << 2) + (lane >> 4);
  int byte = (row << 7) + ((slot ^ (row & 7)) << 4);
  return *(const bf16x8_t*)((const char*)tile + byte);
}

__global__ __launch_bounds__(512, 2)
void k_gemm256(const uint16_t* __restrict__ A, const uint16_t* __restrict__ B,
               float* __restrict__ C, int M, int N, int K) {
  __shared__ __align__(16) uint16_t smem[2][2][256 * 64];  // [buf][A/B][tile]

  // XCD-aware swizzle (512 WGs, divisible by 8)
  int bid = blockIdx.x;
  int cpx = gridDim.x >> 3;
  int wg  = (bid & 7) * cpx + (bid >> 3);
  int ntn = N >> 8;
  int tm = (wg / ntn) << 8;
  int tn = (wg % ntn) << 8;

  int tid  = threadIdx.x;
  int lane = tid & 63;
  int wid  = tid >> 6;
  int wr = wid >> 2;       // 0..1 -> 128-row half of A
  int wc = wid & 3;        // 0..3 -> 64-col slice of B

  f32x4_t acc[8][4] = {};
  bf16x8_t a[4][2], b[4][2];

  const int nt = K >> 6;   // 64 K-tiles of BK=64

  // prologue: stage tiles 0 and 1
  stage_tile(A, tm, 0,  K, &smem[0][0][0], lane, wid);
  stage_tile(B, tn, 0,  K, &smem[0][1][0], lane, wid);
  stage_tile(A, tm, 64, K, &smem[1][0][0], lane, wid);
  stage_tile(B, tn, 64, K, &smem[1][1][0], lane, wid);

#pragma unroll 1
  for (int t = 0; t < nt; ++t) {
    int buf = t & 1;
    // drain this tile's 8 stage loads (8 newer may stay in flight)
    if (t < nt - 1) { asm volatile("s_waitcnt vmcnt(8)" ::: "memory"); }
    else            { asm volatile("s_waitcnt vmcnt(0)" ::: "memory"); }
    __builtin_amdgcn_s_barrier();
    __builtin_amdgcn_sched_barrier(0);

    const uint16_t* At = &smem[buf][0][0];
    const uint16_t* Bt = &smem[buf][1][0];
    int arow0 = (wr << 7) + (lane & 15);
    int brow0 = (wc << 6) + (lane & 15);

    // ---- P1: read A[m0-3], B[n0-1]; MFMA m0-3 x n0-1
#pragma unroll
    for (int m = 0; m < 4; ++m) {
      a[m][0] = read_frag(At, arow0 + (m << 4), 0, lane);
      a[m][1] = read_frag(At, arow0 + (m << 4), 1, lane);
    }
#pragma unroll
    for (int n = 0; n < 2; ++n) {
      b[n][0] = read_frag(Bt, brow0 + (n << 4), 0, lane);
      b[n][1] = read_frag(Bt, brow0 + (n << 4), 1, lane);
    }
    __builtin_amdgcn_s_setprio(1);
#pragma unroll
    for (int m = 0; m < 4; ++m)
#pragma unroll
      for (int n = 0; n < 2; ++n)
#pragma unroll
        for (int kk = 0; kk < 2; ++kk)
          acc[m][n] = __builtin_amdgcn_mfma_f32_16x16x32_bf16(a[m][kk], b[n][kk], acc[m][n], 0, 0, 0);
    __builtin_amdgcn_s_setprio(0);
    __builtin_amdgcn_s_barrier();

    // ---- P2: read B[n2-3]; MFMA m0-3 x n2-3
#pragma unroll
    for (int n = 2; n < 4; ++n) {
      b[n][0] = read_frag(Bt, brow0 + (n << 4), 0, lane);
      b[n][1] = read_frag(Bt, brow0 + (n << 4), 1, lane);
    }
    __builtin_amdgcn_s_setprio(1);
#pragma unroll
    for (int m = 0; m < 4; ++m)
#pragma unroll
      for (int n = 2; n < 4; ++n)
#pragma unroll
        for (int kk = 0; kk < 2; ++kk)
          acc[m][n] = __builtin_amdgcn_mfma_f32_16x16x32_bf16(a[m][kk], b[n][kk], acc[m][n], 0, 0, 0);
    __builtin_amdgcn_s_setprio(0);
    __builtin_amdgcn_s_barrier();

    // ---- P3: read A[m4-7] (reuse regs); MFMA m4-7 x n0-1
#pragma unroll
    for (int m = 0; m < 4; ++m) {
      a[m][0] = read_frag(At, arow0 + ((m + 4) << 4), 0, lane);
      a[m][1] = read_frag(At, arow0 + ((m + 4) << 4), 1, lane);
    }
    __builtin_amdgcn_s_setprio(1);
#pragma unroll
    for (int m = 0; m < 4; ++m)
#pragma unroll
      for (int n = 0; n < 2; ++n)
#pragma unroll
        for (int kk = 0; kk < 2; ++kk)
          acc[m + 4][n] = __builtin_amdgcn_mfma_f32_16x16x32_bf16(a[m][kk], b[n][kk], acc[m + 4][n], 0, 0, 0);
    __builtin_amdgcn_s_setprio(0);
    __builtin_amdgcn_s_barrier();

    // ---- P4: MFMA m4-7 x n2-3
    __builtin_amdgcn_s_setprio(1);
#pragma unroll
    for (int m = 0; m < 4; ++m)
#pragma unroll
      for (int n = 2; n < 4; ++n)
#pragma unroll
        for (int kk = 0; kk < 2; ++kk)
          acc[m + 4][n] = __builtin_amdgcn_mfma_f32_16x16x32_bf16(a[m][kk], b[n][kk], acc[m + 4][n], 0, 0, 0);
    __builtin_amdgcn_s_setprio(0);

    // all reads of buf done -> safe to overwrite after barrier
    __builtin_amdgcn_sched_barrier(0);
    __builtin_amdgcn_s_barrier();
    __builtin_amdgcn_sched_barrier(0);
    if (t + 2 < nt) {
      int k2 = (t + 2) << 6;
      stage_tile(A, tm, k2, K, &smem[buf][0][0], lane, wid);
      stage_tile(B, tn, k2, K, &smem[buf][1][0], lane, wid);
    }
  }

  // epilogue: C/D layout col = lane&15, row = (lane>>4)*4 + j
  int crow = tm + (wr << 7) + ((lane >> 4) << 2);
  int ccol = tn + (wc << 6) + (lane & 15);
#pragma unroll
  for (int m = 0; m < 8; ++m)
#pragma unroll
    for (int n = 0; n < 4; ++n)
#pragma unroll
      for (int j = 0; j < 4; ++j)
        C[(size_t)(crow + (m << 4) + j) * N + (ccol + (n << 4))] = acc[m][n][j];
}

// ---------------- launch ----------------
extern "C" void kernel_launch(void* const* d_in, const int* in_sizes, int n_in,
                              void* d_out, int out_size, void* d_ws, size_t ws_size,
                              hipStream_t stream) {
  const float* x      = (const float*)d_in[0];
  const float* weight = (const float*)d_in[1];
  const float* lA     = (const float*)d_in[2];
  const float* lB     = (const float*)d_in[3];
  float* out = (float*)d_out;

  const int M = 4 * 2048;   // B*S
  const int N = 4096;       // D_OUT
  const int K = 4096;       // D_IN

  size_t need = (size_t)M * K * 2 + (size_t)N * K * 2;
  if (ws_size < need) return;

  uint16_t* xb = (uint16_t*)d_ws;
  uint16_t* wb = xb + (size_t)M * K;

  k_bitflip_x<<<2048, 256, 0, stream>>>((const u32x4*)x, (uint2*)xb, (M * K) / 4);
  k_make_wb<<<2048, 256, 0, stream>>>((const f32x4_v*)weight, lA, lB, (uint2*)wb, (N * K) / 4);

  dim3 grid((M / 256) * (N / 256));   // 512 WGs, divisible by 8
  k_gemm256<<<grid, 512, 0, stream>>>(xb, wb, out, M, N, K);
}